// Round 14
// baseline (429.152 us; speedup 1.0000x reference)
//
#include <hip/hip_runtime.h>
#include <hip/hip_bf16.h>

#define D_MODEL 1024
#define NH 16
#define HD 64
#define BATCH 2
#define SEQ 2048

typedef __attribute__((ext_vector_type(8))) short short8;
typedef __attribute__((ext_vector_type(4))) float floatx4;

static __device__ __forceinline__ short f2bf(float f) {
    __hip_bfloat16 h = __float2bfloat16(f);
    return *reinterpret_cast<short*>(&h);
}
static __device__ __forceinline__ unsigned int pk2bf(float a, float b) {
    float2 t; t.x = a; t.y = b;
    __hip_bfloat162 h2 = __float22bfloat162_rn(t);
    return *reinterpret_cast<unsigned int*>(&h2);
}

// ---------------------------------------------------------------------------
// fused fp32 -> bf16 convert: x (4M), w_qkv (3M), w_fc (1M)
// ---------------------------------------------------------------------------
__global__ __launch_bounds__(256) void cvt_all(
    const float* __restrict__ x, const float* __restrict__ wq,
    const float* __restrict__ wf,
    short* __restrict__ Xb, short* __restrict__ Wqb, short* __restrict__ Wfb)
{
    int i = blockIdx.x * 256 + threadIdx.x;
    const float* src; short* dst; int off;
    if (i < 524288)      { src = x;  dst = Xb;  off = i; }
    else if (i < 917504) { src = wq; dst = Wqb; off = i - 524288; }
    else                 { src = wf; dst = Wfb; off = i - 917504; }
    float4 a = *reinterpret_cast<const float4*>(src + off * 8);
    float4 b = *reinterpret_cast<const float4*>(src + off * 8 + 4);
    short8 o;
    o[0] = f2bf(a.x); o[1] = f2bf(a.y); o[2] = f2bf(a.z); o[3] = f2bf(a.w);
    o[4] = f2bf(b.x); o[5] = f2bf(b.y); o[6] = f2bf(b.z); o[7] = f2bf(b.w);
    *reinterpret_cast<short8*>(dst + off * 8) = o;
}

// ---------------------------------------------------------------------------
// zero-fill Oacc (4M floats) + lacc (64K floats), contiguous
// ---------------------------------------------------------------------------
__global__ __launch_bounds__(256) void zero_fill(float* __restrict__ p)
{
    int i = blockIdx.x * 256 + threadIdx.x;
    *reinterpret_cast<float4*>(p + (size_t)i * 4) = float4{0.f, 0.f, 0.f, 0.f};
}

// ---------------------------------------------------------------------------
// GEMM1: QKV projection (verified). 128x128 tiles, pure-type 64-halves.
// Q scaled by 0.125*log2(e); K -> [b,h,s,d]; V -> [b,h,d,s].
// ---------------------------------------------------------------------------
__global__ __launch_bounds__(256) void qkv_gemm(
    const short* __restrict__ X, const short* __restrict__ W,
    const float* __restrict__ bias,
    short* __restrict__ Qs, short* __restrict__ Ks, short* __restrict__ Vt_g)
{
    __shared__ __align__(16) short As[128][72];
    __shared__ __align__(16) short Bs[128][72];
    const int tid = threadIdx.x;
    const int m0 = blockIdx.y * 128;
    const int n0 = blockIdx.x * 128;
    const int bi = m0 >> 11, sl0 = m0 & 2047;
    const int w = tid >> 6, lane = tid & 63;
    const int quad = lane >> 4, l15 = lane & 15;
    const int wm2 = w >> 1, wn2 = w & 1;

    floatx4 acc[4][4];
#pragma unroll
    for (int i = 0; i < 4; i++)
#pragma unroll
        for (int j = 0; j < 4; j++) acc[i][j] = (floatx4)0.0f;

    for (int k0 = 0; k0 < 1024; k0 += 64) {
        __syncthreads();
#pragma unroll
        for (int i = 0; i < 4; i++) {
            int c = tid + i * 256;
            int row = c >> 3, ck = c & 7;
            *reinterpret_cast<uint4*>(&As[row][ck * 8]) =
                *reinterpret_cast<const uint4*>(&X[(m0 + row) * 1024 + k0 + ck * 8]);
            *reinterpret_cast<uint4*>(&Bs[row][ck * 8]) =
                *reinterpret_cast<const uint4*>(&W[(n0 + row) * 1024 + k0 + ck * 8]);
        }
        __syncthreads();
#pragma unroll
        for (int kk = 0; kk < 2; kk++) {
            short8 a[4], b[4];
#pragma unroll
            for (int t = 0; t < 4; t++) {
                a[t] = *reinterpret_cast<const short8*>(&As[wm2 * 64 + t * 16 + l15][kk * 32 + quad * 8]);
                b[t] = *reinterpret_cast<const short8*>(&Bs[wn2 * 64 + t * 16 + l15][kk * 32 + quad * 8]);
            }
#pragma unroll
            for (int mt = 0; mt < 4; mt++)
#pragma unroll
                for (int nt = 0; nt < 4; nt++)
                    acc[mt][nt] = __builtin_amdgcn_mfma_f32_16x16x32_bf16(
                        a[mt], b[nt], acc[mt][nt], 0, 0, 0);
        }
    }

    __syncthreads();
    short* T = &As[0][0];
#pragma unroll
    for (int half = 0; half < 2; half++) {
        const int colg0 = n0 + half * 64;
        const int h = colg0 / 192;
        const int t = (colg0 % 192) / 64;
        if (wn2 == half) {
#pragma unroll
            for (int nt = 0; nt < 4; nt++) {
                int jj = nt * 16 + l15;
                float bv = bias[colg0 + jj];
#pragma unroll
                for (int mt = 0; mt < 4; mt++) {
#pragma unroll
                    for (int r = 0; r < 4; r++) {
                        int ml = wm2 * 64 + mt * 16 + quad * 4 + r;
                        float v = acc[mt][nt][r] + bv;
                        if (t == 0) v *= 0.18033688f;   // 0.125 * log2(e)
                        if (t < 2) As[ml][jj] = f2bf(v);
                        else       T[jj * 136 + ml] = f2bf(v);
                    }
                }
            }
        }
        __syncthreads();
        if (t < 2) {
            short* dst = (t == 0) ? Qs : Ks;
#pragma unroll
            for (int i = 0; i < 4; i++) {
                int c = tid + i * 256;
                int row = c >> 3, ck = c & 7;
                uint4 u = *reinterpret_cast<const uint4*>(&As[row][ck * 8]);
                *reinterpret_cast<uint4*>(
                    &dst[((size_t)(bi * NH + h) * SEQ + sl0 + row) * HD + ck * 8]) = u;
            }
        } else {
#pragma unroll
            for (int i = 0; i < 4; i++) {
                int c = tid + i * 256;
                int d = c >> 4, ck = c & 15;
                uint4 u = *reinterpret_cast<const uint4*>(&T[d * 136 + ck * 8]);
                *reinterpret_cast<uint4*>(
                    &Vt_g[((size_t)(bi * NH + h) * HD + d) * SEQ + sl0 + ck * 8]) = u;
            }
        }
        __syncthreads();
    }
}

// ---------------------------------------------------------------------------
// Flash attention, K-SPLIT x4, 32-k half-tiles, ~20KB LDS -> 8 blocks/CU.
// Softmax-lite partials accumulate into fp32 Oacc/lacc via atomicAdd
// (each address hit exactly 4x). Per half-tile: 8 QK + 8 PV + 2 ones MFMA.
// ---------------------------------------------------------------------------
__global__ __launch_bounds__(256, 8) void attn_kernel(
    const short* __restrict__ Qs, const short* __restrict__ Ks,
    const short* __restrict__ Vt_g,
    float* __restrict__ Oacc, float* __restrict__ lacc)
{
    __shared__ __align__(16) short Kl[32][72];     // [k_local][d]
    __shared__ __align__(16) short Vt[64][40];     // [d][k_local]
    __shared__ __align__(16) short Pl[4][32][40];  // per-wave P [q_local][k]

    const int tid = threadIdx.x;
    const int w = tid >> 6, lane = tid & 63;
    const int quad = lane >> 4, l15 = lane & 15;
    const int bx = blockIdx.x;              // 64: qblk = bx>>2, split = bx&3
    const int q0 = (bx >> 2) * 128;
    const int kt0 = (bx & 3) * (SEQ / 4);
    const int h = blockIdx.y, bi = blockIdx.z;
    const int bh = bi * NH + h;
    const int kbase = bh * SEQ * HD;        // K/Q: [s][d]
    const int vbase = bh * HD * SEQ;        // V^T: [d][s]

    // staging maps (one uint4 each per half-tile)
    const int krow = tid >> 3, kck = (tid & 7) * 8;   // K: 32 rows x 8 chunks
    const int vd = tid >> 2,   vkc = (tid & 3) * 8;   // V: 64 d-rows x 4 chunks

    const short8 onesv = {(short)0x3F80, (short)0x3F80, (short)0x3F80, (short)0x3F80,
                          (short)0x3F80, (short)0x3F80, (short)0x3F80, (short)0x3F80};

    // Q B-frags for this wave's 32 q (pre-scaled by 0.125*log2e)
    short8 aq[2][2];
#pragma unroll
    for (int qt2 = 0; qt2 < 2; qt2++) {
        const short* qp = Qs + kbase + (q0 + w * 32 + qt2 * 16 + l15) * HD;
#pragma unroll
        for (int c = 0; c < 2; c++)
            aq[qt2][c] = *reinterpret_cast<const short8*>(qp + c * 32 + quad * 8);
    }

    floatx4 o[2][4], ol[2];
#pragma unroll
    for (int mt = 0; mt < 2; mt++) {
        ol[mt] = (floatx4)0.0f;
#pragma unroll
        for (int nt = 0; nt < 4; nt++) o[mt][nt] = (floatx4)0.0f;
    }

    for (int it = 0; it < SEQ / 4 / 32; it++) {   // 16 half-tiles of 32 k
        const int kt = kt0 + it * 32;
        __syncthreads();
        *reinterpret_cast<uint4*>(&Kl[krow][kck]) =
            *reinterpret_cast<const uint4*>(&Ks[kbase + (kt + krow) * HD + kck]);
        *reinterpret_cast<uint4*>(&Vt[vd][vkc]) =
            *reinterpret_cast<const uint4*>(&Vt_g[vbase + vd * SEQ + kt + vkc]);
        __syncthreads();

        // S^T (32k x 32q): lane k = kt2*16+quad*4+r, q = qt2*16+l15
        floatx4 sf[2][2];
#pragma unroll
        for (int kt2 = 0; kt2 < 2; kt2++)
#pragma unroll
            for (int qt2 = 0; qt2 < 2; qt2++) sf[kt2][qt2] = (floatx4)0.0f;
#pragma unroll
        for (int c = 0; c < 2; c++) {
#pragma unroll
            for (int kt2 = 0; kt2 < 2; kt2++) {
                short8 bk = *reinterpret_cast<const short8*>(
                    &Kl[kt2 * 16 + l15][c * 32 + quad * 8]);
#pragma unroll
                for (int qt2 = 0; qt2 < 2; qt2++)
                    sf[kt2][qt2] = __builtin_amdgcn_mfma_f32_16x16x32_bf16(
                        bk, aq[qt2][c], sf[kt2][qt2], 0, 0, 0);
            }
        }

        // p = exp2(s'); pack consecutive-k pairs; b64 P writes
#pragma unroll
        for (int kt2 = 0; kt2 < 2; kt2++) {
#pragma unroll
            for (int qt2 = 0; qt2 < 2; qt2++) {
                uint2 p;
                p.x = pk2bf(exp2f(sf[kt2][qt2][0]), exp2f(sf[kt2][qt2][1]));
                p.y = pk2bf(exp2f(sf[kt2][qt2][2]), exp2f(sf[kt2][qt2][3]));
                *reinterpret_cast<uint2*>(&Pl[w][qt2 * 16 + l15][kt2 * 16 + quad * 4]) = p;
            }
        }
        asm volatile("s_waitcnt lgkmcnt(0)" ::: "memory");  // wave-local Pl fence

        // O += P V (K=32, single step); l += P * ones
#pragma unroll
        for (int mt = 0; mt < 2; mt++) {
            short8 ap = *reinterpret_cast<const short8*>(&Pl[w][mt * 16 + l15][quad * 8]);
#pragma unroll
            for (int nt = 0; nt < 4; nt++) {
                short8 bv = *reinterpret_cast<const short8*>(&Vt[nt * 16 + l15][quad * 8]);
                o[mt][nt] = __builtin_amdgcn_mfma_f32_16x16x32_bf16(
                    ap, bv, o[mt][nt], 0, 0, 0);
            }
            ol[mt] = __builtin_amdgcn_mfma_f32_16x16x32_bf16(
                ap, onesv, ol[mt], 0, 0, 0);
        }
    }

    // epilogue: accumulate partials (each address written by exactly 4 blocks)
#pragma unroll
    for (int mt = 0; mt < 2; mt++) {
#pragma unroll
        for (int r = 0; r < 4; r++) {
            int ql = q0 + w * 32 + mt * 16 + quad * 4 + r;
            float* op = Oacc + ((size_t)bi * SEQ + ql) * D_MODEL + h * HD;
#pragma unroll
            for (int nt = 0; nt < 4; nt++)
                atomicAdd(op + nt * 16 + l15, o[mt][nt][r]);
            if (l15 == 0)
                atomicAdd(lacc + bh * SEQ + ql, ol[mt][r]);
        }
    }
}

// ---------------------------------------------------------------------------
// combine: attnb[m][e] = bf16( Oacc[m][e] / lacc[bh][s] ). 8 elems/thread.
// ---------------------------------------------------------------------------
__global__ __launch_bounds__(256) void combine_kernel(
    const float* __restrict__ Oacc, const float* __restrict__ lacc,
    short* __restrict__ attnb)
{
    int i = blockIdx.x * 256 + threadIdx.x;   // 524288 threads
    int m = i >> 7;                  // row 0..4095
    int e0 = (i & 127) * 8;          // col chunk (8 | 64: single head)
    int bi = m >> 11, s = m & 2047, h = e0 >> 6;
    float rl = 1.0f / lacc[(bi * NH + h) * SEQ + s];
    size_t off = (size_t)m * D_MODEL + e0;
    float4 a = *reinterpret_cast<const float4*>(Oacc + off);
    float4 b = *reinterpret_cast<const float4*>(Oacc + off + 4);
    short8 out;
    out[0] = f2bf(a.x * rl); out[1] = f2bf(a.y * rl);
    out[2] = f2bf(a.z * rl); out[3] = f2bf(a.w * rl);
    out[4] = f2bf(b.x * rl); out[5] = f2bf(b.y * rl);
    out[6] = f2bf(b.z * rl); out[7] = f2bf(b.w * rl);
    *reinterpret_cast<short8*>(attnb + off) = out;
}

// ---------------------------------------------------------------------------
// GEMM2 (unchanged): out[m,e] = sum_k attn[m,k]*Wfc[e,k]+b_fc[e]. fp32 out.
// ---------------------------------------------------------------------------
__global__ __launch_bounds__(256) void fc_gemm(
    const short* __restrict__ A, const short* __restrict__ W,
    const float* __restrict__ bias, float* __restrict__ out)
{
    __shared__ __align__(16) short As[128][72];
    __shared__ __align__(16) short Bs[64][72];
    const int tid = threadIdx.x;
    const int m0 = blockIdx.y * 128;
    const int n0 = blockIdx.x * 64;
    const int w = tid >> 6, lane = tid & 63;
    const int quad = lane >> 4, l15 = lane & 15;
    const int wm2 = w >> 1, wn2 = w & 1;

    floatx4 acc[4][2];
#pragma unroll
    for (int i = 0; i < 4; i++)
#pragma unroll
        for (int j = 0; j < 2; j++) acc[i][j] = (floatx4)0.0f;

    for (int k0 = 0; k0 < 1024; k0 += 64) {
        __syncthreads();
#pragma unroll
        for (int i = 0; i < 4; i++) {
            int c = tid + i * 256;
            int row = c >> 3, ck = c & 7;
            *reinterpret_cast<uint4*>(&As[row][ck * 8]) =
                *reinterpret_cast<const uint4*>(&A[(m0 + row) * 1024 + k0 + ck * 8]);
        }
#pragma unroll
        for (int i = 0; i < 2; i++) {
            int c = tid + i * 256;
            int row = c >> 3, ck = c & 7;
            *reinterpret_cast<uint4*>(&Bs[row][ck * 8]) =
                *reinterpret_cast<const uint4*>(&W[(n0 + row) * 1024 + k0 + ck * 8]);
        }
        __syncthreads();
#pragma unroll
        for (int kk = 0; kk < 2; kk++) {
            short8 a[4], b[2];
#pragma unroll
            for (int i = 0; i < 4; i++)
                a[i] = *reinterpret_cast<const short8*>(&As[wm2 * 64 + i * 16 + l15][kk * 32 + quad * 8]);
#pragma unroll
            for (int j = 0; j < 2; j++)
                b[j] = *reinterpret_cast<const short8*>(&Bs[wn2 * 32 + j * 16 + l15][kk * 32 + quad * 8]);
#pragma unroll
            for (int mt = 0; mt < 4; mt++)
#pragma unroll
                for (int nt = 0; nt < 2; nt++)
                    acc[mt][nt] = __builtin_amdgcn_mfma_f32_16x16x32_bf16(
                        a[mt], b[nt], acc[mt][nt], 0, 0, 0);
        }
    }

#pragma unroll
    for (int nt = 0; nt < 2; nt++) {
        int col = n0 + wn2 * 32 + nt * 16 + l15;
        float bv = bias[col];
#pragma unroll
        for (int mt = 0; mt < 4; mt++) {
#pragma unroll
            for (int r = 0; r < 4; r++) {
                int row = m0 + wm2 * 64 + mt * 16 + quad * 4 + r;
                out[row * 1024 + col] = acc[mt][nt][r] + bv;
            }
        }
    }
}

extern "C" void kernel_launch(void* const* d_in, const int* in_sizes, int n_in,
                              void* d_out, int out_size, void* d_ws, size_t ws_size,
                              hipStream_t stream) {
    const float* x     = (const float*)d_in[0];
    const float* w_qkv = (const float*)d_in[1];
    const float* b_qkv = (const float*)d_in[2];
    const float* w_fc  = (const float*)d_in[3];
    const float* b_fc  = (const float*)d_in[4];
    float* out = (float*)d_out;

    const size_t M1 = 1024u * 1024u;
    short* ws = (short*)d_ws;
    // layout (shorts): Qs[0,4M) Ks[4M,8M) Vt[8M,12M) Wfb[12M,13M)
    //   Xb[13M,17M) Wqb[17M,20M)  (dead after qkv_gemm)
    //   Oacc fp32 4M floats = [13M,21M) shorts (overlaps Xb/Wqb)
    //   lacc fp32 64K floats = [21M,21.125M)   total ~42.3 MB
    short* Qs    = ws;
    short* Ks    = ws + 4 * M1;
    short* Vt_g  = ws + 8 * M1;
    short* Wfb   = ws + 12 * M1;
    short* Xb    = ws + 13 * M1;
    short* Wqb   = ws + 17 * M1;
    float* Oacc  = (float*)(ws + 13 * M1);
    float* lacc  = (float*)(ws + 21 * M1);
    short* attnb = Qs;   // Qs dead after attn

    cvt_all<<<4096, 256, 0, stream>>>(x, w_qkv, w_fc, Xb, Wqb, Wfb);
    qkv_gemm<<<dim3(24, 32), 256, 0, stream>>>(Xb, Wqb, b_qkv, Qs, Ks, Vt_g);
    zero_fill<<<4160, 256, 0, stream>>>(Oacc);   // zeros Oacc + lacc (contiguous)
    attn_kernel<<<dim3(64, 16, 2), 256, 0, stream>>>(Qs, Ks, Vt_g, Oacc, lacc);
    combine_kernel<<<2048, 256, 0, stream>>>(Oacc, lacc, attnb);
    fc_gemm<<<dim3(16, 32), 256, 0, stream>>>(attnb, Wfb, b_fc, out);
}

// Round 15
// 414.899 us; speedup vs baseline: 1.0344x; 1.0344x over previous
//
#include <hip/hip_runtime.h>
#include <hip/hip_bf16.h>
#include <hip/hip_fp16.h>

#define D_MODEL 1024
#define NH 16
#define HD 64
#define BATCH 2
#define SEQ 2048

typedef __attribute__((ext_vector_type(8))) short short8;
typedef __attribute__((ext_vector_type(4))) float floatx4;
typedef __attribute__((ext_vector_type(8))) _Float16 half8;

static __device__ __forceinline__ short f2bf(float f) {
    __hip_bfloat16 h = __float2bfloat16(f);
    return *reinterpret_cast<short*>(&h);
}
static __device__ __forceinline__ unsigned int pk2bf(float a, float b) {
    float2 t; t.x = a; t.y = b;
    __hip_bfloat162 h2 = __float22bfloat162_rn(t);
    return *reinterpret_cast<unsigned int*>(&h2);
}

// ---------------------------------------------------------------------------
// fused fp32 -> bf16 convert: x (4M), w_qkv (3M), w_fc (1M)
// ---------------------------------------------------------------------------
__global__ __launch_bounds__(256) void cvt_all(
    const float* __restrict__ x, const float* __restrict__ wq,
    const float* __restrict__ wf,
    short* __restrict__ Xb, short* __restrict__ Wqb, short* __restrict__ Wfb)
{
    int i = blockIdx.x * 256 + threadIdx.x;
    const float* src; short* dst; int off;
    if (i < 524288)      { src = x;  dst = Xb;  off = i; }
    else if (i < 917504) { src = wq; dst = Wqb; off = i - 524288; }
    else                 { src = wf; dst = Wfb; off = i - 917504; }
    float4 a = *reinterpret_cast<const float4*>(src + off * 8);
    float4 b = *reinterpret_cast<const float4*>(src + off * 8 + 4);
    short8 o;
    o[0] = f2bf(a.x); o[1] = f2bf(a.y); o[2] = f2bf(a.z); o[3] = f2bf(a.w);
    o[4] = f2bf(b.x); o[5] = f2bf(b.y); o[6] = f2bf(b.z); o[7] = f2bf(b.w);
    *reinterpret_cast<short8*>(dst + off * 8) = o;
}

// ---------------------------------------------------------------------------
// GEMM1: QKV projection (verified). 128x128 tiles, pure-type 64-halves.
// Q scaled by 0.125*log2(e); K -> [b,h,s,d]; V -> [b,h,d,s].
// ---------------------------------------------------------------------------
__global__ __launch_bounds__(256) void qkv_gemm(
    const short* __restrict__ X, const short* __restrict__ W,
    const float* __restrict__ bias,
    short* __restrict__ Qs, short* __restrict__ Ks, short* __restrict__ Vt_g)
{
    __shared__ __align__(16) short As[128][72];
    __shared__ __align__(16) short Bs[128][72];
    const int tid = threadIdx.x;
    const int m0 = blockIdx.y * 128;
    const int n0 = blockIdx.x * 128;
    const int bi = m0 >> 11, sl0 = m0 & 2047;
    const int w = tid >> 6, lane = tid & 63;
    const int quad = lane >> 4, l15 = lane & 15;
    const int wm2 = w >> 1, wn2 = w & 1;

    floatx4 acc[4][4];
#pragma unroll
    for (int i = 0; i < 4; i++)
#pragma unroll
        for (int j = 0; j < 4; j++) acc[i][j] = (floatx4)0.0f;

    for (int k0 = 0; k0 < 1024; k0 += 64) {
        __syncthreads();
#pragma unroll
        for (int i = 0; i < 4; i++) {
            int c = tid + i * 256;
            int row = c >> 3, ck = c & 7;
            *reinterpret_cast<uint4*>(&As[row][ck * 8]) =
                *reinterpret_cast<const uint4*>(&X[(m0 + row) * 1024 + k0 + ck * 8]);
            *reinterpret_cast<uint4*>(&Bs[row][ck * 8]) =
                *reinterpret_cast<const uint4*>(&W[(n0 + row) * 1024 + k0 + ck * 8]);
        }
        __syncthreads();
#pragma unroll
        for (int kk = 0; kk < 2; kk++) {
            short8 a[4], b[4];
#pragma unroll
            for (int t = 0; t < 4; t++) {
                a[t] = *reinterpret_cast<const short8*>(&As[wm2 * 64 + t * 16 + l15][kk * 32 + quad * 8]);
                b[t] = *reinterpret_cast<const short8*>(&Bs[wn2 * 64 + t * 16 + l15][kk * 32 + quad * 8]);
            }
#pragma unroll
            for (int mt = 0; mt < 4; mt++)
#pragma unroll
                for (int nt = 0; nt < 4; nt++)
                    acc[mt][nt] = __builtin_amdgcn_mfma_f32_16x16x32_bf16(
                        a[mt], b[nt], acc[mt][nt], 0, 0, 0);
        }
    }

    __syncthreads();
    short* T = &As[0][0];
#pragma unroll
    for (int half = 0; half < 2; half++) {
        const int colg0 = n0 + half * 64;
        const int h = colg0 / 192;
        const int t = (colg0 % 192) / 64;
        if (wn2 == half) {
#pragma unroll
            for (int nt = 0; nt < 4; nt++) {
                int jj = nt * 16 + l15;
                float bv = bias[colg0 + jj];
#pragma unroll
                for (int mt = 0; mt < 4; mt++) {
#pragma unroll
                    for (int r = 0; r < 4; r++) {
                        int ml = wm2 * 64 + mt * 16 + quad * 4 + r;
                        float v = acc[mt][nt][r] + bv;
                        if (t == 0) v *= 0.18033688f;   // 0.125 * log2(e)
                        if (t < 2) As[ml][jj] = f2bf(v);
                        else       T[jj * 136 + ml] = f2bf(v);
                    }
                }
            }
        }
        __syncthreads();
        if (t < 2) {
            short* dst = (t == 0) ? Qs : Ks;
#pragma unroll
            for (int i = 0; i < 4; i++) {
                int c = tid + i * 256;
                int row = c >> 3, ck = c & 7;
                uint4 u = *reinterpret_cast<const uint4*>(&As[row][ck * 8]);
                *reinterpret_cast<uint4*>(
                    &dst[((size_t)(bi * NH + h) * SEQ + sl0 + row) * HD + ck * 8]) = u;
            }
        } else {
#pragma unroll
            for (int i = 0; i < 4; i++) {
                int c = tid + i * 256;
                int d = c >> 4, ck = c & 15;
                uint4 u = *reinterpret_cast<const uint4*>(&T[d * 136 + ck * 8]);
                *reinterpret_cast<uint4*>(
                    &Vt_g[((size_t)(bi * NH + h) * HD + d) * SEQ + sl0 + ck * 8]) = u;
            }
        }
        __syncthreads();
    }
}

// ---------------------------------------------------------------------------
// Flash attention, K-SPLIT x4, 32-k half-tiles, ~20KB LDS -> 8 blocks/CU.
// Each split writes its OWN fp16 O-partial + fp32 l-partial (write-once,
// no atomics). Per half-tile: 8 QK + 8 PV + 2 ones-MFMA (l via MFMA).
// ---------------------------------------------------------------------------
__global__ __launch_bounds__(256, 8) void attn_kernel(
    const short* __restrict__ Qs, const short* __restrict__ Ks,
    const short* __restrict__ Vt_g,
    _Float16* __restrict__ Opart01, _Float16* __restrict__ Opart23,
    float* __restrict__ lpart)
{
    __shared__ __align__(16) short Kl[32][72];     // [k_local][d]
    __shared__ __align__(16) short Vt[64][40];     // [d][k_local]
    __shared__ __align__(16) short Pl[4][32][40];  // per-wave P [q_local][k]

    const int tid = threadIdx.x;
    const int w = tid >> 6, lane = tid & 63;
    const int quad = lane >> 4, l15 = lane & 15;
    const int bx = blockIdx.x;              // 64: qblk = bx>>2, split = bx&3
    const int split = bx & 3;
    const int q0 = (bx >> 2) * 128;
    const int kt0 = split * (SEQ / 4);
    const int h = blockIdx.y, bi = blockIdx.z;
    const int bh = bi * NH + h;
    const int kbase = bh * SEQ * HD;        // K/Q: [s][d]
    const int vbase = bh * HD * SEQ;        // V^T: [d][s]

    const int krow = tid >> 3, kck = (tid & 7) * 8;   // K: 32 rows x 8 chunks
    const int vd = tid >> 2,   vkc = (tid & 3) * 8;   // V: 64 d-rows x 4 chunks

    const short8 onesv = {(short)0x3F80, (short)0x3F80, (short)0x3F80, (short)0x3F80,
                          (short)0x3F80, (short)0x3F80, (short)0x3F80, (short)0x3F80};

    short8 aq[2][2];
#pragma unroll
    for (int qt2 = 0; qt2 < 2; qt2++) {
        const short* qp = Qs + kbase + (q0 + w * 32 + qt2 * 16 + l15) * HD;
#pragma unroll
        for (int c = 0; c < 2; c++)
            aq[qt2][c] = *reinterpret_cast<const short8*>(qp + c * 32 + quad * 8);
    }

    floatx4 o[2][4], ol[2];
#pragma unroll
    for (int mt = 0; mt < 2; mt++) {
        ol[mt] = (floatx4)0.0f;
#pragma unroll
        for (int nt = 0; nt < 4; nt++) o[mt][nt] = (floatx4)0.0f;
    }

    for (int it = 0; it < SEQ / 4 / 32; it++) {   // 16 half-tiles of 32 k
        const int kt = kt0 + it * 32;
        __syncthreads();
        *reinterpret_cast<uint4*>(&Kl[krow][kck]) =
            *reinterpret_cast<const uint4*>(&Ks[kbase + (kt + krow) * HD + kck]);
        *reinterpret_cast<uint4*>(&Vt[vd][vkc]) =
            *reinterpret_cast<const uint4*>(&Vt_g[vbase + vd * SEQ + kt + vkc]);
        __syncthreads();

        // S^T (32k x 32q)
        floatx4 sf[2][2];
#pragma unroll
        for (int kt2 = 0; kt2 < 2; kt2++)
#pragma unroll
            for (int qt2 = 0; qt2 < 2; qt2++) sf[kt2][qt2] = (floatx4)0.0f;
#pragma unroll
        for (int c = 0; c < 2; c++) {
#pragma unroll
            for (int kt2 = 0; kt2 < 2; kt2++) {
                short8 bk = *reinterpret_cast<const short8*>(
                    &Kl[kt2 * 16 + l15][c * 32 + quad * 8]);
#pragma unroll
                for (int qt2 = 0; qt2 < 2; qt2++)
                    sf[kt2][qt2] = __builtin_amdgcn_mfma_f32_16x16x32_bf16(
                        bk, aq[qt2][c], sf[kt2][qt2], 0, 0, 0);
            }
        }

        // p = exp2(s'); packed b64 P writes
#pragma unroll
        for (int kt2 = 0; kt2 < 2; kt2++) {
#pragma unroll
            for (int qt2 = 0; qt2 < 2; qt2++) {
                uint2 p;
                p.x = pk2bf(exp2f(sf[kt2][qt2][0]), exp2f(sf[kt2][qt2][1]));
                p.y = pk2bf(exp2f(sf[kt2][qt2][2]), exp2f(sf[kt2][qt2][3]));
                *reinterpret_cast<uint2*>(&Pl[w][qt2 * 16 + l15][kt2 * 16 + quad * 4]) = p;
            }
        }
        asm volatile("s_waitcnt lgkmcnt(0)" ::: "memory");  // wave-local Pl fence

        // O += P V (K=32 single step); l += P * ones
#pragma unroll
        for (int mt = 0; mt < 2; mt++) {
            short8 ap = *reinterpret_cast<const short8*>(&Pl[w][mt * 16 + l15][quad * 8]);
#pragma unroll
            for (int nt = 0; nt < 4; nt++) {
                short8 bv = *reinterpret_cast<const short8*>(&Vt[nt * 16 + l15][quad * 8]);
                o[mt][nt] = __builtin_amdgcn_mfma_f32_16x16x32_bf16(
                    ap, bv, o[mt][nt], 0, 0, 0);
            }
            ol[mt] = __builtin_amdgcn_mfma_f32_16x16x32_bf16(
                ap, onesv, ol[mt], 0, 0, 0);
        }
    }

    // epilogue: write this split's fp16 O-partial + fp32 l-partial (no RMW)
    _Float16* Obuf = ((split < 2) ? Opart01 : Opart23) +
                     (size_t)(split & 1) * (4096u * 1024u);
#pragma unroll
    for (int mt = 0; mt < 2; mt++) {
#pragma unroll
        for (int r = 0; r < 4; r++) {
            int ql = q0 + w * 32 + mt * 16 + quad * 4 + r;
            size_t base = ((size_t)bi * SEQ + ql) * D_MODEL + h * HD;
#pragma unroll
            for (int nt = 0; nt < 4; nt++)
                Obuf[base + nt * 16 + l15] = (_Float16)o[mt][nt][r];
            if (l15 == 0)
                lpart[split * 65536 + bh * SEQ + ql] = ol[mt][r];
        }
    }
}

// ---------------------------------------------------------------------------
// combine: attnb = bf16( (O0+O1+O2+O3) / (l0+l1+l2+l3) ). 8 elems/thread.
// ---------------------------------------------------------------------------
__global__ __launch_bounds__(256) void combine_kernel(
    const _Float16* __restrict__ O01, const _Float16* __restrict__ O23,
    const float* __restrict__ lp, short* __restrict__ attnb)
{
    int i = blockIdx.x * 256 + threadIdx.x;   // 524288 threads
    int m = i >> 7;                  // row 0..4095
    int e0 = (i & 127) * 8;          // col chunk (8 | 64: single head)
    int bi = m >> 11, s = m & 2047, h = e0 >> 6;
    int li = (bi * NH + h) * SEQ + s;
    float l = lp[li] + lp[65536 + li] + lp[131072 + li] + lp[196608 + li];
    float rl = 1.0f / l;
    size_t off = (size_t)m * D_MODEL + e0;
    half8 a0 = *reinterpret_cast<const half8*>(O01 + off);
    half8 a1 = *reinterpret_cast<const half8*>(O01 + 4096u * 1024u + off);
    half8 a2 = *reinterpret_cast<const half8*>(O23 + off);
    half8 a3 = *reinterpret_cast<const half8*>(O23 + 4096u * 1024u + off);
    short8 out;
#pragma unroll
    for (int j = 0; j < 8; j++)
        out[j] = f2bf(((float)a0[j] + (float)a1[j] + (float)a2[j] + (float)a3[j]) * rl);
    *reinterpret_cast<short8*>(attnb + off) = out;
}

// ---------------------------------------------------------------------------
// GEMM2 (unchanged): out[m,e] = sum_k attn[m,k]*Wfc[e,k]+b_fc[e]. fp32 out.
// ---------------------------------------------------------------------------
__global__ __launch_bounds__(256) void fc_gemm(
    const short* __restrict__ A, const short* __restrict__ W,
    const float* __restrict__ bias, float* __restrict__ out)
{
    __shared__ __align__(16) short As[128][72];
    __shared__ __align__(16) short Bs[64][72];
    const int tid = threadIdx.x;
    const int m0 = blockIdx.y * 128;
    const int n0 = blockIdx.x * 64;
    const int w = tid >> 6, lane = tid & 63;
    const int quad = lane >> 4, l15 = lane & 15;
    const int wm2 = w >> 1, wn2 = w & 1;

    floatx4 acc[4][2];
#pragma unroll
    for (int i = 0; i < 4; i++)
#pragma unroll
        for (int j = 0; j < 2; j++) acc[i][j] = (floatx4)0.0f;

    for (int k0 = 0; k0 < 1024; k0 += 64) {
        __syncthreads();
#pragma unroll
        for (int i = 0; i < 4; i++) {
            int c = tid + i * 256;
            int row = c >> 3, ck = c & 7;
            *reinterpret_cast<uint4*>(&As[row][ck * 8]) =
                *reinterpret_cast<const uint4*>(&A[(m0 + row) * 1024 + k0 + ck * 8]);
        }
#pragma unroll
        for (int i = 0; i < 2; i++) {
            int c = tid + i * 256;
            int row = c >> 3, ck = c & 7;
            *reinterpret_cast<uint4*>(&Bs[row][ck * 8]) =
                *reinterpret_cast<const uint4*>(&W[(n0 + row) * 1024 + k0 + ck * 8]);
        }
        __syncthreads();
#pragma unroll
        for (int kk = 0; kk < 2; kk++) {
            short8 a[4], b[2];
#pragma unroll
            for (int i = 0; i < 4; i++)
                a[i] = *reinterpret_cast<const short8*>(&As[wm2 * 64 + i * 16 + l15][kk * 32 + quad * 8]);
#pragma unroll
            for (int j = 0; j < 2; j++)
                b[j] = *reinterpret_cast<const short8*>(&Bs[wn2 * 32 + j * 16 + l15][kk * 32 + quad * 8]);
#pragma unroll
            for (int mt = 0; mt < 4; mt++)
#pragma unroll
                for (int nt = 0; nt < 2; nt++)
                    acc[mt][nt] = __builtin_amdgcn_mfma_f32_16x16x32_bf16(
                        a[mt], b[nt], acc[mt][nt], 0, 0, 0);
        }
    }

#pragma unroll
    for (int nt = 0; nt < 2; nt++) {
        int col = n0 + wn2 * 32 + nt * 16 + l15;
        float bv = bias[col];
#pragma unroll
        for (int mt = 0; mt < 4; mt++) {
#pragma unroll
            for (int r = 0; r < 4; r++) {
                int row = m0 + wm2 * 64 + mt * 16 + quad * 4 + r;
                out[row * 1024 + col] = acc[mt][nt][r] + bv;
            }
        }
    }
}

extern "C" void kernel_launch(void* const* d_in, const int* in_sizes, int n_in,
                              void* d_out, int out_size, void* d_ws, size_t ws_size,
                              hipStream_t stream) {
    const float* x     = (const float*)d_in[0];
    const float* w_qkv = (const float*)d_in[1];
    const float* b_qkv = (const float*)d_in[2];
    const float* w_fc  = (const float*)d_in[3];
    const float* b_fc  = (const float*)d_in[4];
    float* out = (float*)d_out;

    const size_t M1 = 1024u * 1024u;
    short* ws = (short*)d_ws;
    // layout (shorts): Qs[0,4M) Ks[4M,8M) Vt[8M,12M) Wfb[12M,13M)
    //   Xb[13M,17M) Wqb[17M,20M) (dead after qkv)
    //   Opart01 fp16 8M elems = [13M,21M) shorts (overlaps Xb/Wqb)
    //   lpart fp32 256K floats = [21M,21.5M)  -> ws total 43 MB
    //   Opart23 fp16 8M elems = d_out (16 MB; overwritten before combine,
    //   then rewritten by fc_gemm after combine has consumed it)
    short* Qs    = ws;
    short* Ks    = ws + 4 * M1;
    short* Vt_g  = ws + 8 * M1;
    short* Wfb   = ws + 12 * M1;
    short* Xb    = ws + 13 * M1;
    short* Wqb   = ws + 17 * M1;
    _Float16* Opart01 = (_Float16*)(ws + 13 * M1);
    _Float16* Opart23 = (_Float16*)d_out;
    float* lpart = (float*)(ws + 21 * M1);
    short* attnb = Qs;   // Qs dead after attn

    cvt_all<<<4096, 256, 0, stream>>>(x, w_qkv, w_fc, Xb, Wqb, Wfb);
    qkv_gemm<<<dim3(24, 32), 256, 0, stream>>>(Xb, Wqb, b_qkv, Qs, Ks, Vt_g);
    attn_kernel<<<dim3(64, 16, 2), 256, 0, stream>>>(Qs, Ks, Vt_g,
                                                     Opart01, Opart23, lpart);
    combine_kernel<<<2048, 256, 0, stream>>>(Opart01, Opart23, lpart, attnb);
    fc_gemm<<<dim3(16, 32), 256, 0, stream>>>(attnb, Wfb, b_fc, out);
}

// Round 16
// 217.392 us; speedup vs baseline: 1.9741x; 1.9085x over previous
//
#include <hip/hip_runtime.h>
#include <hip/hip_bf16.h>
#include <hip/hip_fp16.h>

#define D_MODEL 1024
#define NH 16
#define HD 64
#define BATCH 2
#define SEQ 2048

typedef __attribute__((ext_vector_type(8))) short short8;
typedef __attribute__((ext_vector_type(4))) float floatx4;
typedef __attribute__((ext_vector_type(8))) _Float16 half8;

static __device__ __forceinline__ short f2bf(float f) {
    __hip_bfloat16 h = __float2bfloat16(f);
    return *reinterpret_cast<short*>(&h);
}
static __device__ __forceinline__ unsigned int pk2bf(float a, float b) {
    float2 t; t.x = a; t.y = b;
    __hip_bfloat162 h2 = __float22bfloat162_rn(t);
    return *reinterpret_cast<unsigned int*>(&h2);
}

#define GLDS(gp, lp) __builtin_amdgcn_global_load_lds( \
    (const __attribute__((address_space(1))) void*)(gp), \
    (__attribute__((address_space(3))) void*)(lp), 16, 0, 0)

// ---------------------------------------------------------------------------
// fused fp32 -> bf16 convert: x (4M), w_qkv (3M), w_fc (1M)
// ---------------------------------------------------------------------------
__global__ __launch_bounds__(256) void cvt_all(
    const float* __restrict__ x, const float* __restrict__ wq,
    const float* __restrict__ wf,
    short* __restrict__ Xb, short* __restrict__ Wqb, short* __restrict__ Wfb)
{
    int i = blockIdx.x * 256 + threadIdx.x;
    const float* src; short* dst; int off;
    if (i < 524288)      { src = x;  dst = Xb;  off = i; }
    else if (i < 917504) { src = wq; dst = Wqb; off = i - 524288; }
    else                 { src = wf; dst = Wfb; off = i - 917504; }
    float4 a = *reinterpret_cast<const float4*>(src + off * 8);
    float4 b = *reinterpret_cast<const float4*>(src + off * 8 + 4);
    short8 o;
    o[0] = f2bf(a.x); o[1] = f2bf(a.y); o[2] = f2bf(a.z); o[3] = f2bf(a.w);
    o[4] = f2bf(b.x); o[5] = f2bf(b.y); o[6] = f2bf(b.z); o[7] = f2bf(b.w);
    *reinterpret_cast<short8*>(dst + off * 8) = o;
}

// ---------------------------------------------------------------------------
// GEMM1: QKV projection. 128x128 tiles; global_load_lds(16B) staging into
// UNPADDED LDS with XOR-swizzled chunks (global chunk c of row r -> LDS slot
// c^(r&7)); frag reads use slot (4kk+quad)^(l15&7) -> 2-way banks (free).
// Epilogue (unchanged, stride-72/136 views): Q*0.125*log2e; K; V transposed.
// ---------------------------------------------------------------------------
__global__ __launch_bounds__(256) void qkv_gemm(
    const short* __restrict__ X, const short* __restrict__ W,
    const float* __restrict__ bias,
    short* __restrict__ Qs, short* __restrict__ Ks, short* __restrict__ Vt_g)
{
    __shared__ __align__(16) short As[128][72];   // staging uses first 8192 linear
    __shared__ __align__(16) short Bs[128 * 64];
    const int tid = threadIdx.x;
    const int m0 = blockIdx.y * 128;
    const int n0 = blockIdx.x * 128;
    const int bi = m0 >> 11, sl0 = m0 & 2047;
    const int w = tid >> 6, lane = tid & 63;
    const int quad = lane >> 4, l15 = lane & 15;
    const int wm2 = w >> 1, wn2 = w & 1;
    short* Asl = &As[0][0];

    const int rg = lane >> 3;          // row in 8-row group
    const int sl = lane & 7;           // LDS 16B slot
    const int cg = sl ^ rg;            // swizzled global chunk

    floatx4 acc[4][4];
#pragma unroll
    for (int i = 0; i < 4; i++)
#pragma unroll
        for (int j = 0; j < 4; j++) acc[i][j] = (floatx4)0.0f;

    for (int k0 = 0; k0 < 1024; k0 += 64) {
        __syncthreads();
#pragma unroll
        for (int j = 0; j < 4; j++) {
            int g = w * 4 + j;                 // 8-row group 0..15
            int r = g * 8 + rg;
            GLDS(&X[(size_t)(m0 + r) * 1024 + k0 + cg * 8], &Asl[g * 512]);
            GLDS(&W[(size_t)(n0 + r) * 1024 + k0 + cg * 8], &Bs[g * 512]);
        }
        __syncthreads();
#pragma unroll
        for (int kk = 0; kk < 2; kk++) {
            short8 a[4], b[4];
#pragma unroll
            for (int t = 0; t < 4; t++) {
                int swz = ((kk * 4 + quad) ^ (l15 & 7)) * 8;
                a[t] = *reinterpret_cast<const short8*>(
                    &Asl[(wm2 * 64 + t * 16 + l15) * 64 + swz]);
                b[t] = *reinterpret_cast<const short8*>(
                    &Bs[(wn2 * 64 + t * 16 + l15) * 64 + swz]);
            }
#pragma unroll
            for (int mt = 0; mt < 4; mt++)
#pragma unroll
                for (int nt = 0; nt < 4; nt++)
                    acc[mt][nt] = __builtin_amdgcn_mfma_f32_16x16x32_bf16(
                        a[mt], b[nt], acc[mt][nt], 0, 0, 0);
        }
    }

    __syncthreads();
    short* T = &As[0][0];   // [64][136] view for V transpose (<= 9216 shorts)
#pragma unroll
    for (int half = 0; half < 2; half++) {
        const int colg0 = n0 + half * 64;
        const int h = colg0 / 192;
        const int t = (colg0 % 192) / 64;
        if (wn2 == half) {
#pragma unroll
            for (int nt = 0; nt < 4; nt++) {
                int jj = nt * 16 + l15;
                float bv = bias[colg0 + jj];
#pragma unroll
                for (int mt = 0; mt < 4; mt++) {
#pragma unroll
                    for (int r = 0; r < 4; r++) {
                        int ml = wm2 * 64 + mt * 16 + quad * 4 + r;
                        float v = acc[mt][nt][r] + bv;
                        if (t == 0) v *= 0.18033688f;   // 0.125 * log2(e)
                        if (t < 2) As[ml][jj] = f2bf(v);
                        else       T[jj * 136 + ml] = f2bf(v);
                    }
                }
            }
        }
        __syncthreads();
        if (t < 2) {
            short* dst = (t == 0) ? Qs : Ks;
#pragma unroll
            for (int i = 0; i < 4; i++) {
                int c = tid + i * 256;
                int row = c >> 3, ck = c & 7;
                uint4 u = *reinterpret_cast<const uint4*>(&As[row][ck * 8]);
                *reinterpret_cast<uint4*>(
                    &dst[((size_t)(bi * NH + h) * SEQ + sl0 + row) * HD + ck * 8]) = u;
            }
        } else {
#pragma unroll
            for (int i = 0; i < 4; i++) {
                int c = tid + i * 256;
                int d = c >> 4, ck = c & 15;
                uint4 u = *reinterpret_cast<const uint4*>(&T[d * 136 + ck * 8]);
                *reinterpret_cast<uint4*>(
                    &Vt_g[((size_t)(bi * NH + h) * HD + d) * SEQ + sl0 + ck * 8]) = u;
            }
        }
        __syncthreads();
    }
}

// ---------------------------------------------------------------------------
// Flash attention (R13-exact, proven 70us): K-SPLIT x2, softmax-lite,
// 128 q/block, single-buffered 64-k tiles, l via ones-MFMA,
// unnormalized fp16 O + fp32 l partials.
// ---------------------------------------------------------------------------
__global__ __launch_bounds__(256, 4) void attn_kernel(
    const short* __restrict__ Qs, const short* __restrict__ Ks,
    const short* __restrict__ Vt_g,
    _Float16* __restrict__ Opart, float* __restrict__ lpart)
{
    __shared__ __align__(16) short Kl[64][72];     // [k_local][d]
    __shared__ __align__(16) short Vt[64][72];     // [d][k_local]
    __shared__ __align__(16) short Pl[4][32][72];  // per-wave P [q_local][k]

    const int tid = threadIdx.x;
    const int w = tid >> 6, lane = tid & 63;
    const int quad = lane >> 4, l15 = lane & 15;
    const int bx = blockIdx.x;              // 32: qblk = bx>>1, khalf = bx&1
    const int khalf = bx & 1;
    const int q0 = (bx >> 1) * 128;
    const int h = blockIdx.y, bi = blockIdx.z;
    const int bh = bi * NH + h;
    const int kbase = bh * SEQ * HD;        // K/Q: [s][d]
    const int vbase = bh * HD * SEQ;        // V^T: [d][s]
    const int kt0 = khalf * (SEQ / 2);

    const int kr0 = tid >> 3,         kc0 = (tid & 7) * 8;
    const int kr1 = (tid + 256) >> 3, kc1 = (tid & 7) * 8;  // rows 32..63

    const short8 onesv = {(short)0x3F80, (short)0x3F80, (short)0x3F80, (short)0x3F80,
                          (short)0x3F80, (short)0x3F80, (short)0x3F80, (short)0x3F80};

    short8 aq[2][2];
#pragma unroll
    for (int qt2 = 0; qt2 < 2; qt2++) {
        const short* qp = Qs + kbase + (q0 + w * 32 + qt2 * 16 + l15) * HD;
#pragma unroll
        for (int c = 0; c < 2; c++)
            aq[qt2][c] = *reinterpret_cast<const short8*>(qp + c * 32 + quad * 8);
    }

    floatx4 o[2][4], ol[2];
#pragma unroll
    for (int mt = 0; mt < 2; mt++) {
        ol[mt] = (floatx4)0.0f;
#pragma unroll
        for (int nt = 0; nt < 4; nt++) o[mt][nt] = (floatx4)0.0f;
    }

    for (int it = 0; it < SEQ / 128; it++) {   // 16 tiles of 64 k
        const int kt = kt0 + it * 64;
        __syncthreads();
        *reinterpret_cast<uint4*>(&Kl[kr0][kc0]) =
            *reinterpret_cast<const uint4*>(&Ks[kbase + (kt + kr0) * HD + kc0]);
        *reinterpret_cast<uint4*>(&Kl[kr1][kc1]) =
            *reinterpret_cast<const uint4*>(&Ks[kbase + (kt + kr1) * HD + kc1]);
        *reinterpret_cast<uint4*>(&Vt[kr0][kc0]) =
            *reinterpret_cast<const uint4*>(&Vt_g[vbase + kr0 * SEQ + kt + kc0]);
        *reinterpret_cast<uint4*>(&Vt[kr1][kc1]) =
            *reinterpret_cast<const uint4*>(&Vt_g[vbase + kr1 * SEQ + kt + kc1]);
        __syncthreads();

        floatx4 sf[4][2];
#pragma unroll
        for (int kt2 = 0; kt2 < 4; kt2++)
#pragma unroll
            for (int qt2 = 0; qt2 < 2; qt2++) sf[kt2][qt2] = (floatx4)0.0f;
#pragma unroll
        for (int c = 0; c < 2; c++) {
#pragma unroll
            for (int kt2 = 0; kt2 < 4; kt2++) {
                short8 bk = *reinterpret_cast<const short8*>(
                    &Kl[kt2 * 16 + l15][c * 32 + quad * 8]);
#pragma unroll
                for (int qt2 = 0; qt2 < 2; qt2++)
                    sf[kt2][qt2] = __builtin_amdgcn_mfma_f32_16x16x32_bf16(
                        bk, aq[qt2][c], sf[kt2][qt2], 0, 0, 0);
            }
        }

#pragma unroll
        for (int kt2 = 0; kt2 < 4; kt2++) {
#pragma unroll
            for (int qt2 = 0; qt2 < 2; qt2++) {
                uint2 p;
                p.x = pk2bf(exp2f(sf[kt2][qt2][0]), exp2f(sf[kt2][qt2][1]));
                p.y = pk2bf(exp2f(sf[kt2][qt2][2]), exp2f(sf[kt2][qt2][3]));
                *reinterpret_cast<uint2*>(&Pl[w][qt2 * 16 + l15][kt2 * 16 + quad * 4]) = p;
            }
        }
        asm volatile("s_waitcnt lgkmcnt(0)" ::: "memory");  // wave-local Pl fence

#pragma unroll
        for (int c = 0; c < 2; c++) {
            short8 vf[4];
#pragma unroll
            for (int nt = 0; nt < 4; nt++)
                vf[nt] = *reinterpret_cast<const short8*>(
                    &Vt[nt * 16 + l15][c * 32 + quad * 8]);
#pragma unroll
            for (int mt = 0; mt < 2; mt++) {
                short8 ap = *reinterpret_cast<const short8*>(
                    &Pl[w][mt * 16 + l15][c * 32 + quad * 8]);
#pragma unroll
                for (int nt = 0; nt < 4; nt++)
                    o[mt][nt] = __builtin_amdgcn_mfma_f32_16x16x32_bf16(
                        ap, vf[nt], o[mt][nt], 0, 0, 0);
                ol[mt] = __builtin_amdgcn_mfma_f32_16x16x32_bf16(
                    ap, onesv, ol[mt], 0, 0, 0);
            }
        }
    }

#pragma unroll
    for (int mt = 0; mt < 2; mt++) {
#pragma unroll
        for (int r = 0; r < 4; r++) {
            int ql = q0 + w * 32 + mt * 16 + quad * 4 + r;
            size_t base = (size_t)khalf * (4096u * 1024u) +
                          ((size_t)bi * SEQ + ql) * D_MODEL + h * HD;
#pragma unroll
            for (int nt = 0; nt < 4; nt++)
                Opart[base + nt * 16 + l15] = (_Float16)o[mt][nt][r];
            if (l15 == 0)
                lpart[khalf * 65536 + bh * SEQ + ql] = ol[mt][r];
        }
    }
}

// ---------------------------------------------------------------------------
// combine: attnb[m][e] = bf16( (O1+O2)/(l1+l2) ). 8 elems/thread.
// ---------------------------------------------------------------------------
__global__ __launch_bounds__(256) void combine_kernel(
    const _Float16* __restrict__ O, const float* __restrict__ lp,
    short* __restrict__ attnb)
{
    int i = blockIdx.x * 256 + threadIdx.x;   // 524288 threads
    int m = i >> 7;
    int e0 = (i & 127) * 8;
    int bi = m >> 11, s = m & 2047, h = e0 >> 6;
    int bh = bi * NH + h;
    float l = lp[bh * SEQ + s] + lp[65536 + bh * SEQ + s];
    float rl = 1.0f / l;
    size_t off = (size_t)m * D_MODEL + e0;
    half8 a = *reinterpret_cast<const half8*>(O + off);
    half8 b = *reinterpret_cast<const half8*>(O + 4096u * 1024u + off);
    short8 out;
#pragma unroll
    for (int j = 0; j < 8; j++)
        out[j] = f2bf(((float)a[j] + (float)b[j]) * rl);
    *reinterpret_cast<short8*>(attnb + off) = out;
}

// ---------------------------------------------------------------------------
// GEMM2: 128m x 64n tiles, global_load_lds + XOR swizzle staging. fp32 out.
// ---------------------------------------------------------------------------
__global__ __launch_bounds__(256) void fc_gemm(
    const short* __restrict__ A, const short* __restrict__ W,
    const float* __restrict__ bias, float* __restrict__ out)
{
    __shared__ __align__(16) short As[128 * 64];
    __shared__ __align__(16) short Bs[64 * 64];
    const int tid = threadIdx.x;
    const int m0 = blockIdx.y * 128;
    const int n0 = blockIdx.x * 64;
    const int w = tid >> 6, lane = tid & 63;
    const int quad = lane >> 4, l15 = lane & 15;
    const int wm2 = w >> 1, wn2 = w & 1;

    const int rg = lane >> 3;
    const int sl = lane & 7;
    const int cg = sl ^ rg;

    floatx4 acc[4][2];
#pragma unroll
    for (int i = 0; i < 4; i++)
#pragma unroll
        for (int j = 0; j < 2; j++) acc[i][j] = (floatx4)0.0f;

    for (int k0 = 0; k0 < 1024; k0 += 64) {
        __syncthreads();
#pragma unroll
        for (int j = 0; j < 4; j++) {          // A: 16 groups of 8 rows
            int g = w * 4 + j;
            int r = g * 8 + rg;
            GLDS(&A[(size_t)(m0 + r) * 1024 + k0 + cg * 8], &As[g * 512]);
        }
#pragma unroll
        for (int j = 0; j < 2; j++) {          // B: 8 groups of 8 rows
            int g = w * 2 + j;
            int r = g * 8 + rg;
            GLDS(&W[(size_t)(n0 + r) * 1024 + k0 + cg * 8], &Bs[g * 512]);
        }
        __syncthreads();
#pragma unroll
        for (int kk = 0; kk < 2; kk++) {
            int swz = ((kk * 4 + quad) ^ (l15 & 7)) * 8;
            short8 a[4], b[2];
#pragma unroll
            for (int i = 0; i < 4; i++)
                a[i] = *reinterpret_cast<const short8*>(
                    &As[(wm2 * 64 + i * 16 + l15) * 64 + swz]);
#pragma unroll
            for (int j = 0; j < 2; j++)
                b[j] = *reinterpret_cast<const short8*>(
                    &Bs[(wn2 * 32 + j * 16 + l15) * 64 + swz]);
#pragma unroll
            for (int mt = 0; mt < 4; mt++)
#pragma unroll
                for (int nt = 0; nt < 2; nt++)
                    acc[mt][nt] = __builtin_amdgcn_mfma_f32_16x16x32_bf16(
                        a[mt], b[nt], acc[mt][nt], 0, 0, 0);
        }
    }

#pragma unroll
    for (int nt = 0; nt < 2; nt++) {
        int col = n0 + wn2 * 32 + nt * 16 + l15;
        float bv = bias[col];
#pragma unroll
        for (int mt = 0; mt < 4; mt++) {
#pragma unroll
            for (int r = 0; r < 4; r++) {
                int row = m0 + wm2 * 64 + mt * 16 + quad * 4 + r;
                out[row * 1024 + col] = acc[mt][nt][r] + bv;
            }
        }
    }
}

extern "C" void kernel_launch(void* const* d_in, const int* in_sizes, int n_in,
                              void* d_out, int out_size, void* d_ws, size_t ws_size,
                              hipStream_t stream) {
    const float* x     = (const float*)d_in[0];
    const float* w_qkv = (const float*)d_in[1];
    const float* b_qkv = (const float*)d_in[2];
    const float* w_fc  = (const float*)d_in[3];
    const float* b_fc  = (const float*)d_in[4];
    float* out = (float*)d_out;

    const size_t M1 = 1024u * 1024u;
    short* ws = (short*)d_ws;
    // layout (shorts): Qs[0,4M) Ks[4M,8M) Vt[8M,12M) Wfb[12M,13M)
    //   Xb[13M,17M) Wqb[17M,20M) (dead after qkv)
    //   Opart fp16 8M elems = [13M,21M) shorts (overlaps Xb/Wqb)
    //   lpart fp32 128K floats = [21M,21.25M)   total 42.5 MB
    short* Qs    = ws;
    short* Ks    = ws + 4 * M1;
    short* Vt_g  = ws + 8 * M1;
    short* Wfb   = ws + 12 * M1;
    short* Xb    = ws + 13 * M1;
    short* Wqb   = ws + 17 * M1;
    _Float16* Opart = (_Float16*)(ws + 13 * M1);
    float* lpart = (float*)(ws + 21 * M1);
    short* attnb = Qs;   // Qs dead after attn

    cvt_all<<<4096, 256, 0, stream>>>(x, w_qkv, w_fc, Xb, Wqb, Wfb);
    qkv_gemm<<<dim3(24, 32), 256, 0, stream>>>(Xb, Wqb, b_qkv, Qs, Ks, Vt_g);
    attn_kernel<<<dim3(32, 16, 2), 256, 0, stream>>>(Qs, Ks, Vt_g, Opart, lpart);
    combine_kernel<<<2048, 256, 0, stream>>>(Opart, lpart, attnb);
    fc_gemm<<<dim3(16, 32), 256, 0, stream>>>(attnb, Wfb, b_fc, out);
}

// Round 18
// 215.440 us; speedup vs baseline: 1.9920x; 1.0091x over previous
//
#include <hip/hip_runtime.h>
#include <hip/hip_bf16.h>
#include <hip/hip_fp16.h>

#define D_MODEL 1024
#define NH 16
#define HD 64
#define BATCH 2
#define SEQ 2048

typedef __attribute__((ext_vector_type(8))) short short8;
typedef __attribute__((ext_vector_type(4))) float floatx4;
typedef __attribute__((ext_vector_type(8))) _Float16 half8;

static __device__ __forceinline__ short f2bf(float f) {
    __hip_bfloat16 h = __float2bfloat16(f);
    return *reinterpret_cast<short*>(&h);
}
static __device__ __forceinline__ unsigned int pk2bf(float a, float b) {
    float2 t; t.x = a; t.y = b;
    __hip_bfloat162 h2 = __float22bfloat162_rn(t);
    return *reinterpret_cast<unsigned int*>(&h2);
}

#define GLDS(gp, lp) __builtin_amdgcn_global_load_lds( \
    (const __attribute__((address_space(1))) void*)(gp), \
    (__attribute__((address_space(3))) void*)(lp), 16, 0, 0)

// ---------------------------------------------------------------------------
// fused fp32 -> bf16 convert: x (4M), w_qkv (3M), w_fc (1M)
// ---------------------------------------------------------------------------
__global__ __launch_bounds__(256) void cvt_all(
    const float* __restrict__ x, const float* __restrict__ wq,
    const float* __restrict__ wf,
    short* __restrict__ Xb, short* __restrict__ Wqb, short* __restrict__ Wfb)
{
    int i = blockIdx.x * 256 + threadIdx.x;
    const float* src; short* dst; int off;
    if (i < 524288)      { src = x;  dst = Xb;  off = i; }
    else if (i < 917504) { src = wq; dst = Wqb; off = i - 524288; }
    else                 { src = wf; dst = Wfb; off = i - 917504; }
    float4 a = *reinterpret_cast<const float4*>(src + off * 8);
    float4 b = *reinterpret_cast<const float4*>(src + off * 8 + 4);
    short8 o;
    o[0] = f2bf(a.x); o[1] = f2bf(a.y); o[2] = f2bf(a.z); o[3] = f2bf(a.w);
    o[4] = f2bf(b.x); o[5] = f2bf(b.y); o[6] = f2bf(b.z); o[7] = f2bf(b.w);
    *reinterpret_cast<short8*>(dst + off * 8) = o;
}

// ---------------------------------------------------------------------------
// GEMM1 (R16-exact): 128x128 tiles; global_load_lds(16B) + XOR swizzle.
// Q*0.125*log2e -> [b,h,s,d]; K -> [b,h,s,d]; V -> [b,h,d,s].
// ---------------------------------------------------------------------------
__global__ __launch_bounds__(256) void qkv_gemm(
    const short* __restrict__ X, const short* __restrict__ W,
    const float* __restrict__ bias,
    short* __restrict__ Qs, short* __restrict__ Ks, short* __restrict__ Vt_g)
{
    __shared__ __align__(16) short As[128][72];
    __shared__ __align__(16) short Bs[128 * 64];
    const int tid = threadIdx.x;
    const int m0 = blockIdx.y * 128;
    const int n0 = blockIdx.x * 128;
    const int bi = m0 >> 11, sl0 = m0 & 2047;
    const int w = tid >> 6, lane = tid & 63;
    const int quad = lane >> 4, l15 = lane & 15;
    const int wm2 = w >> 1, wn2 = w & 1;
    short* Asl = &As[0][0];

    const int rg = lane >> 3;
    const int sl = lane & 7;
    const int cg = sl ^ rg;

    floatx4 acc[4][4];
#pragma unroll
    for (int i = 0; i < 4; i++)
#pragma unroll
        for (int j = 0; j < 4; j++) acc[i][j] = (floatx4)0.0f;

    for (int k0 = 0; k0 < 1024; k0 += 64) {
        __syncthreads();
#pragma unroll
        for (int j = 0; j < 4; j++) {
            int g = w * 4 + j;
            int r = g * 8 + rg;
            GLDS(&X[(size_t)(m0 + r) * 1024 + k0 + cg * 8], &Asl[g * 512]);
            GLDS(&W[(size_t)(n0 + r) * 1024 + k0 + cg * 8], &Bs[g * 512]);
        }
        __syncthreads();
#pragma unroll
        for (int kk = 0; kk < 2; kk++) {
            short8 a[4], b[4];
#pragma unroll
            for (int t = 0; t < 4; t++) {
                int swz = ((kk * 4 + quad) ^ (l15 & 7)) * 8;
                a[t] = *reinterpret_cast<const short8*>(
                    &Asl[(wm2 * 64 + t * 16 + l15) * 64 + swz]);
                b[t] = *reinterpret_cast<const short8*>(
                    &Bs[(wn2 * 64 + t * 16 + l15) * 64 + swz]);
            }
#pragma unroll
            for (int mt = 0; mt < 4; mt++)
#pragma unroll
                for (int nt = 0; nt < 4; nt++)
                    acc[mt][nt] = __builtin_amdgcn_mfma_f32_16x16x32_bf16(
                        a[mt], b[nt], acc[mt][nt], 0, 0, 0);
        }
    }

    __syncthreads();
    short* T = &As[0][0];
#pragma unroll
    for (int half = 0; half < 2; half++) {
        const int colg0 = n0 + half * 64;
        const int h = colg0 / 192;
        const int t = (colg0 % 192) / 64;
        if (wn2 == half) {
#pragma unroll
            for (int nt = 0; nt < 4; nt++) {
                int jj = nt * 16 + l15;
                float bv = bias[colg0 + jj];
#pragma unroll
                for (int mt = 0; mt < 4; mt++) {
#pragma unroll
                    for (int r = 0; r < 4; r++) {
                        int ml = wm2 * 64 + mt * 16 + quad * 4 + r;
                        float v = acc[mt][nt][r] + bv;
                        if (t == 0) v *= 0.18033688f;   // 0.125 * log2(e)
                        if (t < 2) As[ml][jj] = f2bf(v);
                        else       T[jj * 136 + ml] = f2bf(v);
                    }
                }
            }
        }
        __syncthreads();
        if (t < 2) {
            short* dst = (t == 0) ? Qs : Ks;
#pragma unroll
            for (int i = 0; i < 4; i++) {
                int c = tid + i * 256;
                int row = c >> 3, ck = c & 7;
                uint4 u = *reinterpret_cast<const uint4*>(&As[row][ck * 8]);
                *reinterpret_cast<uint4*>(
                    &dst[((size_t)(bi * NH + h) * SEQ + sl0 + row) * HD + ck * 8]) = u;
            }
        } else {
#pragma unroll
            for (int i = 0; i < 4; i++) {
                int c = tid + i * 256;
                int d = c >> 4, ck = c & 15;
                uint4 u = *reinterpret_cast<const uint4*>(&T[d * 136 + ck * 8]);
                *reinterpret_cast<uint4*>(
                    &Vt_g[((size_t)(bi * NH + h) * HD + d) * SEQ + sl0 + ck * 8]) = u;
            }
        }
        __syncthreads();
    }
}

// ---------------------------------------------------------------------------
// Flash attention, 64 q PER WAVE (256 q/block, 4 waves), K-SPLIT x2.
// bk/vf frag reads amortized over 4 qt2. Pl stride 72 (FIX: was 40 in R17,
// overflowed at k>=40). LDS 55.3KB -> 2 blocks/CU.
// Softmax-lite; l via ones-MFMA; unnormalized fp16 O + fp32 l partials.
// ---------------------------------------------------------------------------
__global__ __launch_bounds__(256, 2) void attn_kernel(
    const short* __restrict__ Qs, const short* __restrict__ Ks,
    const short* __restrict__ Vt_g,
    _Float16* __restrict__ Opart, float* __restrict__ lpart)
{
    __shared__ __align__(16) short Kl[64][72];     // [k_local][d]
    __shared__ __align__(16) short Vt[64][72];     // [d][k_local]
    __shared__ __align__(16) short Pl[4][64][72];  // per-wave P [q_local][k]

    const int tid = threadIdx.x;
    const int w = tid >> 6, lane = tid & 63;
    const int quad = lane >> 4, l15 = lane & 15;
    const int bx = blockIdx.x;              // 16: qblk = bx>>1, khalf = bx&1
    const int khalf = bx & 1;
    const int q0 = (bx >> 1) * 256;
    const int h = blockIdx.y, bi = blockIdx.z;
    const int bh = bi * NH + h;
    const int kbase = bh * SEQ * HD;        // K/Q: [s][d]
    const int vbase = bh * HD * SEQ;        // V^T: [d][s]
    const int kt0 = khalf * (SEQ / 2);

    const int kr0 = tid >> 3,         kc0 = (tid & 7) * 8;
    const int kr1 = (tid + 256) >> 3, kc1 = (tid & 7) * 8;  // rows 32..63

    const short8 onesv = {(short)0x3F80, (short)0x3F80, (short)0x3F80, (short)0x3F80,
                          (short)0x3F80, (short)0x3F80, (short)0x3F80, (short)0x3F80};

    // Q B-frags: 64 q per wave (qt2 = 0..3), pre-scaled by 0.125*log2e
    short8 aq[4][2];
#pragma unroll
    for (int qt2 = 0; qt2 < 4; qt2++) {
        const short* qp = Qs + kbase + (q0 + w * 64 + qt2 * 16 + l15) * HD;
#pragma unroll
        for (int c = 0; c < 2; c++)
            aq[qt2][c] = *reinterpret_cast<const short8*>(qp + c * 32 + quad * 8);
    }

    floatx4 o[4][4], ol[4];
#pragma unroll
    for (int qt2 = 0; qt2 < 4; qt2++) {
        ol[qt2] = (floatx4)0.0f;
#pragma unroll
        for (int nt = 0; nt < 4; nt++) o[qt2][nt] = (floatx4)0.0f;
    }

    for (int it = 0; it < SEQ / 128; it++) {   // 16 tiles of 64 k
        const int kt = kt0 + it * 64;
        __syncthreads();
        *reinterpret_cast<uint4*>(&Kl[kr0][kc0]) =
            *reinterpret_cast<const uint4*>(&Ks[kbase + (kt + kr0) * HD + kc0]);
        *reinterpret_cast<uint4*>(&Kl[kr1][kc1]) =
            *reinterpret_cast<const uint4*>(&Ks[kbase + (kt + kr1) * HD + kc1]);
        *reinterpret_cast<uint4*>(&Vt[kr0][kc0]) =
            *reinterpret_cast<const uint4*>(&Vt_g[vbase + kr0 * SEQ + kt + kc0]);
        *reinterpret_cast<uint4*>(&Vt[kr1][kc1]) =
            *reinterpret_cast<const uint4*>(&Vt_g[vbase + kr1 * SEQ + kt + kc1]);
        __syncthreads();

        // K frags once per tile, reused across 4 qt2
        short8 bk[4][2];
#pragma unroll
        for (int kt2 = 0; kt2 < 4; kt2++)
#pragma unroll
            for (int c = 0; c < 2; c++)
                bk[kt2][c] = *reinterpret_cast<const short8*>(
                    &Kl[kt2 * 16 + l15][c * 32 + quad * 8]);

        // per qt2: S^T (64k x 16q) -> exp2 -> packed P write
#pragma unroll
        for (int qt2 = 0; qt2 < 4; qt2++) {
            floatx4 sf[4];
#pragma unroll
            for (int kt2 = 0; kt2 < 4; kt2++) sf[kt2] = (floatx4)0.0f;
#pragma unroll
            for (int c = 0; c < 2; c++)
#pragma unroll
                for (int kt2 = 0; kt2 < 4; kt2++)
                    sf[kt2] = __builtin_amdgcn_mfma_f32_16x16x32_bf16(
                        bk[kt2][c], aq[qt2][c], sf[kt2], 0, 0, 0);
#pragma unroll
            for (int kt2 = 0; kt2 < 4; kt2++) {
                uint2 p;
                p.x = pk2bf(exp2f(sf[kt2][0]), exp2f(sf[kt2][1]));
                p.y = pk2bf(exp2f(sf[kt2][2]), exp2f(sf[kt2][3]));
                *reinterpret_cast<uint2*>(
                    &Pl[w][qt2 * 16 + l15][kt2 * 16 + quad * 4]) = p;
            }
        }
        asm volatile("s_waitcnt lgkmcnt(0)" ::: "memory");  // wave-local Pl fence

        // O += P V ; l += P * ones   (vf shared across qt2)
#pragma unroll
        for (int c = 0; c < 2; c++) {
            short8 vf[4];
#pragma unroll
            for (int nt = 0; nt < 4; nt++)
                vf[nt] = *reinterpret_cast<const short8*>(
                    &Vt[nt * 16 + l15][c * 32 + quad * 8]);
#pragma unroll
            for (int qt2 = 0; qt2 < 4; qt2++) {
                short8 ap = *reinterpret_cast<const short8*>(
                    &Pl[w][qt2 * 16 + l15][c * 32 + quad * 8]);
#pragma unroll
                for (int nt = 0; nt < 4; nt++)
                    o[qt2][nt] = __builtin_amdgcn_mfma_f32_16x16x32_bf16(
                        ap, vf[nt], o[qt2][nt], 0, 0, 0);
                ol[qt2] = __builtin_amdgcn_mfma_f32_16x16x32_bf16(
                    ap, onesv, ol[qt2], 0, 0, 0);
            }
        }
    }

    // epilogue: unnormalized fp16 O + fp32 l partials (per split half)
#pragma unroll
    for (int qt2 = 0; qt2 < 4; qt2++) {
#pragma unroll
        for (int r = 0; r < 4; r++) {
            int ql = q0 + w * 64 + qt2 * 16 + quad * 4 + r;
            size_t base = (size_t)khalf * (4096u * 1024u) +
                          ((size_t)bi * SEQ + ql) * D_MODEL + h * HD;
#pragma unroll
            for (int nt = 0; nt < 4; nt++)
                Opart[base + nt * 16 + l15] = (_Float16)o[qt2][nt][r];
            if (l15 == 0)
                lpart[khalf * 65536 + bh * SEQ + ql] = ol[qt2][r];
        }
    }
}

// ---------------------------------------------------------------------------
// combine: attnb[m][e] = bf16( (O1+O2)/(l1+l2) ). 8 elems/thread.
// ---------------------------------------------------------------------------
__global__ __launch_bounds__(256) void combine_kernel(
    const _Float16* __restrict__ O, const float* __restrict__ lp,
    short* __restrict__ attnb)
{
    int i = blockIdx.x * 256 + threadIdx.x;
    int m = i >> 7;
    int e0 = (i & 127) * 8;
    int bi = m >> 11, s = m & 2047, h = e0 >> 6;
    int bh = bi * NH + h;
    float l = lp[bh * SEQ + s] + lp[65536 + bh * SEQ + s];
    float rl = 1.0f / l;
    size_t off = (size_t)m * D_MODEL + e0;
    half8 a = *reinterpret_cast<const half8*>(O + off);
    half8 b = *reinterpret_cast<const half8*>(O + 4096u * 1024u + off);
    short8 out;
#pragma unroll
    for (int j = 0; j < 8; j++)
        out[j] = f2bf(((float)a[j] + (float)b[j]) * rl);
    *reinterpret_cast<short8*>(attnb + off) = out;
}

// ---------------------------------------------------------------------------
// GEMM2 (R16-exact): 128m x 64n, global_load_lds + XOR swizzle. fp32 out.
// ---------------------------------------------------------------------------
__global__ __launch_bounds__(256) void fc_gemm(
    const short* __restrict__ A, const short* __restrict__ W,
    const float* __restrict__ bias, float* __restrict__ out)
{
    __shared__ __align__(16) short As[128 * 64];
    __shared__ __align__(16) short Bs[64 * 64];
    const int tid = threadIdx.x;
    const int m0 = blockIdx.y * 128;
    const int n0 = blockIdx.x * 64;
    const int w = tid >> 6, lane = tid & 63;
    const int quad = lane >> 4, l15 = lane & 15;
    const int wm2 = w >> 1, wn2 = w & 1;

    const int rg = lane >> 3;
    const int sl = lane & 7;
    const int cg = sl ^ rg;

    floatx4 acc[4][2];
#pragma unroll
    for (int i = 0; i < 4; i++)
#pragma unroll
        for (int j = 0; j < 2; j++) acc[i][j] = (floatx4)0.0f;

    for (int k0 = 0; k0 < 1024; k0 += 64) {
        __syncthreads();
#pragma unroll
        for (int j = 0; j < 4; j++) {
            int g = w * 4 + j;
            int r = g * 8 + rg;
            GLDS(&A[(size_t)(m0 + r) * 1024 + k0 + cg * 8], &As[g * 512]);
        }
#pragma unroll
        for (int j = 0; j < 2; j++) {
            int g = w * 2 + j;
            int r = g * 8 + rg;
            GLDS(&W[(size_t)(n0 + r) * 1024 + k0 + cg * 8], &Bs[g * 512]);
        }
        __syncthreads();
#pragma unroll
        for (int kk = 0; kk < 2; kk++) {
            int swz = ((kk * 4 + quad) ^ (l15 & 7)) * 8;
            short8 a[4], b[2];
#pragma unroll
            for (int i = 0; i < 4; i++)
                a[i] = *reinterpret_cast<const short8*>(
                    &As[(wm2 * 64 + i * 16 + l15) * 64 + swz]);
#pragma unroll
            for (int j = 0; j < 2; j++)
                b[j] = *reinterpret_cast<const short8*>(
                    &Bs[(wn2 * 32 + j * 16 + l15) * 64 + swz]);
#pragma unroll
            for (int mt = 0; mt < 4; mt++)
#pragma unroll
                for (int nt = 0; nt < 2; nt++)
                    acc[mt][nt] = __builtin_amdgcn_mfma_f32_16x16x32_bf16(
                        a[mt], b[nt], acc[mt][nt], 0, 0, 0);
        }
    }

#pragma unroll
    for (int nt = 0; nt < 2; nt++) {
        int col = n0 + wn2 * 32 + nt * 16 + l15;
        float bv = bias[col];
#pragma unroll
        for (int mt = 0; mt < 4; mt++) {
#pragma unroll
            for (int r = 0; r < 4; r++) {
                int row = m0 + wm2 * 64 + mt * 16 + quad * 4 + r;
                out[row * 1024 + col] = acc[mt][nt][r] + bv;
            }
        }
    }
}

extern "C" void kernel_launch(void* const* d_in, const int* in_sizes, int n_in,
                              void* d_out, int out_size, void* d_ws, size_t ws_size,
                              hipStream_t stream) {
    const float* x     = (const float*)d_in[0];
    const float* w_qkv = (const float*)d_in[1];
    const float* b_qkv = (const float*)d_in[2];
    const float* w_fc  = (const float*)d_in[3];
    const float* b_fc  = (const float*)d_in[4];
    float* out = (float*)d_out;

    const size_t M1 = 1024u * 1024u;
    short* ws = (short*)d_ws;
    // layout (shorts): Qs[0,4M) Ks[4M,8M) Vt[8M,12M) Wfb[12M,13M)
    //   Xb[13M,17M) Wqb[17M,20M) (dead after qkv)
    //   Opart fp16 8M elems = [13M,21M) shorts (overlaps Xb/Wqb)
    //   lpart fp32 128K floats = [21M,21.25M)   total 42.5 MB
    short* Qs    = ws;
    short* Ks    = ws + 4 * M1;
    short* Vt_g  = ws + 8 * M1;
    short* Wfb   = ws + 12 * M1;
    short* Xb    = ws + 13 * M1;
    short* Wqb   = ws + 17 * M1;
    _Float16* Opart = (_Float16*)(ws + 13 * M1);
    float* lpart = (float*)(ws + 21 * M1);
    short* attnb = Qs;   // Qs dead after attn

    cvt_all<<<4096, 256, 0, stream>>>(x, w_qkv, w_fc, Xb, Wqb, Wfb);
    qkv_gemm<<<dim3(24, 32), 256, 0, stream>>>(Xb, Wqb, b_qkv, Qs, Ks, Vt_g);
    attn_kernel<<<dim3(16, 16, 2), 256, 0, stream>>>(Qs, Ks, Vt_g, Opart, lpart);
    combine_kernel<<<2048, 256, 0, stream>>>(Opart, lpart, attnb);
    fc_gemm<<<dim3(16, 32), 256, 0, stream>>>(attnb, Wfb, b_fc, out);
}

// Round 19
// 208.353 us; speedup vs baseline: 2.0597x; 1.0340x over previous
//
#include <hip/hip_runtime.h>
#include <hip/hip_bf16.h>
#include <hip/hip_fp16.h>

#define D_MODEL 1024
#define NH 16
#define HD 64
#define BATCH 2
#define SEQ 2048

typedef __attribute__((ext_vector_type(8))) short short8;
typedef __attribute__((ext_vector_type(4))) float floatx4;
typedef __attribute__((ext_vector_type(8))) _Float16 half8;

static __device__ __forceinline__ short f2bf(float f) {
    __hip_bfloat16 h = __float2bfloat16(f);
    return *reinterpret_cast<short*>(&h);
}
static __device__ __forceinline__ unsigned int pk2bf(float a, float b) {
    float2 t; t.x = a; t.y = b;
    __hip_bfloat162 h2 = __float22bfloat162_rn(t);
    return *reinterpret_cast<unsigned int*>(&h2);
}

#define GLDS(gp, lp) __builtin_amdgcn_global_load_lds( \
    (const __attribute__((address_space(1))) void*)(gp), \
    (__attribute__((address_space(3))) void*)(lp), 16, 0, 0)

// ---------------------------------------------------------------------------
// fused fp32 -> bf16 convert: x (4M), w_qkv (3M), w_fc (1M)
// ---------------------------------------------------------------------------
__global__ __launch_bounds__(256) void cvt_all(
    const float* __restrict__ x, const float* __restrict__ wq,
    const float* __restrict__ wf,
    short* __restrict__ Xb, short* __restrict__ Wqb, short* __restrict__ Wfb)
{
    int i = blockIdx.x * 256 + threadIdx.x;
    const float* src; short* dst; int off;
    if (i < 524288)      { src = x;  dst = Xb;  off = i; }
    else if (i < 917504) { src = wq; dst = Wqb; off = i - 524288; }
    else                 { src = wf; dst = Wfb; off = i - 917504; }
    float4 a = *reinterpret_cast<const float4*>(src + off * 8);
    float4 b = *reinterpret_cast<const float4*>(src + off * 8 + 4);
    short8 o;
    o[0] = f2bf(a.x); o[1] = f2bf(a.y); o[2] = f2bf(a.z); o[3] = f2bf(a.w);
    o[4] = f2bf(b.x); o[5] = f2bf(b.y); o[6] = f2bf(b.z); o[7] = f2bf(b.w);
    *reinterpret_cast<short8*>(dst + off * 8) = o;
}

// ---------------------------------------------------------------------------
// GEMM1: QKV projection. 128x128 tiles, BK=128 (8 iters, 64 MFMA/wave/drain),
// global_load_lds(16B) + XOR swizzle, XCD-clustered block mapping:
// lin -> g=lin&7 (XCD), n-tile = g+8*j3 (j3=loc%3), m-tile = loc/3.
// Each XCD keeps 3 W-tiles L2-resident; X-tile reused 3x back-to-back.
// Q*0.125*log2e -> [b,h,s,d]; K -> [b,h,s,d]; V -> [b,h,d,s].
// ---------------------------------------------------------------------------
__global__ __launch_bounds__(256) void qkv_gemm(
    const short* __restrict__ X, const short* __restrict__ W,
    const float* __restrict__ bias,
    short* __restrict__ Qs, short* __restrict__ Ks, short* __restrict__ Vt_g)
{
    __shared__ __align__(16) short As[128 * 128];   // 32 KB
    __shared__ __align__(16) short Bs[128 * 128];   // 32 KB
    const int tid = threadIdx.x;

    // XCD-clustered decode
    const int lin = blockIdx.x;
    const int g = lin & 7;
    const int loc = lin >> 3;         // 0..95
    const int mi = loc / 3;           // 0..31
    const int j3 = loc - mi * 3;      // 0..2
    const int m0 = mi * 128;
    const int n0 = (g + 8 * j3) * 128;
    const int bi = m0 >> 11, sl0 = m0 & 2047;

    const int w = tid >> 6, lane = tid & 63;
    const int quad = lane >> 4, l15 = lane & 15;
    const int wm2 = w >> 1, wn2 = w & 1;

    const int rg = lane >> 3;          // row in 8-row group
    const int sl = lane & 7;           // LDS 16B slot
    const int cg = sl ^ rg;            // swizzled global chunk

    floatx4 acc[4][4];
#pragma unroll
    for (int i = 0; i < 4; i++)
#pragma unroll
        for (int j = 0; j < 4; j++) acc[i][j] = (floatx4)0.0f;

    for (int k0 = 0; k0 < 1024; k0 += 128) {
        __syncthreads();
#pragma unroll
        for (int jj = 0; jj < 4; jj++) {
            int grp = w * 4 + jj;              // 16 groups of 8 rows
            int r = grp * 8 + rg;
#pragma unroll
            for (int kh = 0; kh < 2; kh++) {
                GLDS(&X[(size_t)(m0 + r) * 1024 + k0 + kh * 64 + cg * 8],
                     &As[grp * 1024 + kh * 512]);
                GLDS(&W[(size_t)(n0 + r) * 1024 + k0 + kh * 64 + cg * 8],
                     &Bs[grp * 1024 + kh * 512]);
            }
        }
        __syncthreads();
        // LDS addr of (row r, k word kw): (r>>3)*1024 + (kw>>6)*512 +
        //   (r&7)*64 + ((chunk)^(r&7))*8, chunk = (kw&63)>>3
#pragma unroll
        for (int kk = 0; kk < 4; kk++) {
            const int kw = kk * 32 + quad * 8;
            const int base = (kw >> 6) * 512 +
                             ((((kw & 63) >> 3) ^ (l15 & 7)) * 8);
            short8 a[4], b[4];
#pragma unroll
            for (int t = 0; t < 4; t++) {
                int ra = wm2 * 64 + t * 16 + l15;
                int rb = wn2 * 64 + t * 16 + l15;
                a[t] = *reinterpret_cast<const short8*>(
                    &As[(ra >> 3) * 1024 + (ra & 7) * 64 + base]);
                b[t] = *reinterpret_cast<const short8*>(
                    &Bs[(rb >> 3) * 1024 + (rb & 7) * 64 + base]);
            }
#pragma unroll
            for (int mt = 0; mt < 4; mt++)
#pragma unroll
                for (int nt = 0; nt < 4; nt++)
                    acc[mt][nt] = __builtin_amdgcn_mfma_f32_16x16x32_bf16(
                        a[mt], b[nt], acc[mt][nt], 0, 0, 0);
        }
    }

    __syncthreads();
    short* EA = &As[0];      // [128][72] row-major bounce view (9216 shorts)
    short* T  = &As[0];      // [64][136] transposed view for V (8704 shorts)
#pragma unroll
    for (int half = 0; half < 2; half++) {
        const int colg0 = n0 + half * 64;
        const int h = colg0 / 192;
        const int t = (colg0 % 192) / 64;
        if (wn2 == half) {
#pragma unroll
            for (int nt = 0; nt < 4; nt++) {
                int jj = nt * 16 + l15;
                float bv = bias[colg0 + jj];
#pragma unroll
                for (int mt = 0; mt < 4; mt++) {
#pragma unroll
                    for (int r = 0; r < 4; r++) {
                        int ml = wm2 * 64 + mt * 16 + quad * 4 + r;
                        float v = acc[mt][nt][r] + bv;
                        if (t == 0) v *= 0.18033688f;   // 0.125 * log2(e)
                        if (t < 2) EA[ml * 72 + jj] = f2bf(v);
                        else       T[jj * 136 + ml] = f2bf(v);
                    }
                }
            }
        }
        __syncthreads();
        if (t < 2) {
            short* dst = (t == 0) ? Qs : Ks;
#pragma unroll
            for (int i = 0; i < 4; i++) {       // 128 rows x 8 chunks
                int c = tid + i * 256;
                int row = c >> 3, ck = c & 7;
                uint4 u = *reinterpret_cast<const uint4*>(&EA[row * 72 + ck * 8]);
                *reinterpret_cast<uint4*>(
                    &dst[((size_t)(bi * NH + h) * SEQ + sl0 + row) * HD + ck * 8]) = u;
            }
        } else {
#pragma unroll
            for (int i = 0; i < 4; i++) {       // 64 d-rows x 16 chunks
                int c = tid + i * 256;
                int d = c >> 4, ck = c & 15;
                uint4 u = *reinterpret_cast<const uint4*>(&T[d * 136 + ck * 8]);
                *reinterpret_cast<uint4*>(
                    &Vt_g[((size_t)(bi * NH + h) * HD + d) * SEQ + sl0 + ck * 8]) = u;
            }
        }
        __syncthreads();
    }
}

// ---------------------------------------------------------------------------
// Flash attention (R18-exact): 64 q/wave (256 q/block), K-SPLIT x2,
// Pl stride 72, softmax-lite, l via ones-MFMA, fp16 O + fp32 l partials.
// ---------------------------------------------------------------------------
__global__ __launch_bounds__(256, 2) void attn_kernel(
    const short* __restrict__ Qs, const short* __restrict__ Ks,
    const short* __restrict__ Vt_g,
    _Float16* __restrict__ Opart, float* __restrict__ lpart)
{
    __shared__ __align__(16) short Kl[64][72];     // [k_local][d]
    __shared__ __align__(16) short Vt[64][72];     // [d][k_local]
    __shared__ __align__(16) short Pl[4][64][72];  // per-wave P [q_local][k]

    const int tid = threadIdx.x;
    const int w = tid >> 6, lane = tid & 63;
    const int quad = lane >> 4, l15 = lane & 15;
    const int bx = blockIdx.x;              // 16: qblk = bx>>1, khalf = bx&1
    const int khalf = bx & 1;
    const int q0 = (bx >> 1) * 256;
    const int h = blockIdx.y, bi = blockIdx.z;
    const int bh = bi * NH + h;
    const int kbase = bh * SEQ * HD;        // K/Q: [s][d]
    const int vbase = bh * HD * SEQ;        // V^T: [d][s]
    const int kt0 = khalf * (SEQ / 2);

    const int kr0 = tid >> 3,         kc0 = (tid & 7) * 8;
    const int kr1 = (tid + 256) >> 3, kc1 = (tid & 7) * 8;  // rows 32..63

    const short8 onesv = {(short)0x3F80, (short)0x3F80, (short)0x3F80, (short)0x3F80,
                          (short)0x3F80, (short)0x3F80, (short)0x3F80, (short)0x3F80};

    short8 aq[4][2];
#pragma unroll
    for (int qt2 = 0; qt2 < 4; qt2++) {
        const short* qp = Qs + kbase + (q0 + w * 64 + qt2 * 16 + l15) * HD;
#pragma unroll
        for (int c = 0; c < 2; c++)
            aq[qt2][c] = *reinterpret_cast<const short8*>(qp + c * 32 + quad * 8);
    }

    floatx4 o[4][4], ol[4];
#pragma unroll
    for (int qt2 = 0; qt2 < 4; qt2++) {
        ol[qt2] = (floatx4)0.0f;
#pragma unroll
        for (int nt = 0; nt < 4; nt++) o[qt2][nt] = (floatx4)0.0f;
    }

    for (int it = 0; it < SEQ / 128; it++) {   // 16 tiles of 64 k
        const int kt = kt0 + it * 64;
        __syncthreads();
        *reinterpret_cast<uint4*>(&Kl[kr0][kc0]) =
            *reinterpret_cast<const uint4*>(&Ks[kbase + (kt + kr0) * HD + kc0]);
        *reinterpret_cast<uint4*>(&Kl[kr1][kc1]) =
            *reinterpret_cast<const uint4*>(&Ks[kbase + (kt + kr1) * HD + kc1]);
        *reinterpret_cast<uint4*>(&Vt[kr0][kc0]) =
            *reinterpret_cast<const uint4*>(&Vt_g[vbase + kr0 * SEQ + kt + kc0]);
        *reinterpret_cast<uint4*>(&Vt[kr1][kc1]) =
            *reinterpret_cast<const uint4*>(&Vt_g[vbase + kr1 * SEQ + kt + kc1]);
        __syncthreads();

        short8 bk[4][2];
#pragma unroll
        for (int kt2 = 0; kt2 < 4; kt2++)
#pragma unroll
            for (int c = 0; c < 2; c++)
                bk[kt2][c] = *reinterpret_cast<const short8*>(
                    &Kl[kt2 * 16 + l15][c * 32 + quad * 8]);

#pragma unroll
        for (int qt2 = 0; qt2 < 4; qt2++) {
            floatx4 sf[4];
#pragma unroll
            for (int kt2 = 0; kt2 < 4; kt2++) sf[kt2] = (floatx4)0.0f;
#pragma unroll
            for (int c = 0; c < 2; c++)
#pragma unroll
                for (int kt2 = 0; kt2 < 4; kt2++)
                    sf[kt2] = __builtin_amdgcn_mfma_f32_16x16x32_bf16(
                        bk[kt2][c], aq[qt2][c], sf[kt2], 0, 0, 0);
#pragma unroll
            for (int kt2 = 0; kt2 < 4; kt2++) {
                uint2 p;
                p.x = pk2bf(exp2f(sf[kt2][0]), exp2f(sf[kt2][1]));
                p.y = pk2bf(exp2f(sf[kt2][2]), exp2f(sf[kt2][3]));
                *reinterpret_cast<uint2*>(
                    &Pl[w][qt2 * 16 + l15][kt2 * 16 + quad * 4]) = p;
            }
        }
        asm volatile("s_waitcnt lgkmcnt(0)" ::: "memory");  // wave-local Pl fence

#pragma unroll
        for (int c = 0; c < 2; c++) {
            short8 vf[4];
#pragma unroll
            for (int nt = 0; nt < 4; nt++)
                vf[nt] = *reinterpret_cast<const short8*>(
                    &Vt[nt * 16 + l15][c * 32 + quad * 8]);
#pragma unroll
            for (int qt2 = 0; qt2 < 4; qt2++) {
                short8 ap = *reinterpret_cast<const short8*>(
                    &Pl[w][qt2 * 16 + l15][c * 32 + quad * 8]);
#pragma unroll
                for (int nt = 0; nt < 4; nt++)
                    o[qt2][nt] = __builtin_amdgcn_mfma_f32_16x16x32_bf16(
                        ap, vf[nt], o[qt2][nt], 0, 0, 0);
                ol[qt2] = __builtin_amdgcn_mfma_f32_16x16x32_bf16(
                    ap, onesv, ol[qt2], 0, 0, 0);
            }
        }
    }

#pragma unroll
    for (int qt2 = 0; qt2 < 4; qt2++) {
#pragma unroll
        for (int r = 0; r < 4; r++) {
            int ql = q0 + w * 64 + qt2 * 16 + quad * 4 + r;
            size_t base = (size_t)khalf * (4096u * 1024u) +
                          ((size_t)bi * SEQ + ql) * D_MODEL + h * HD;
#pragma unroll
            for (int nt = 0; nt < 4; nt++)
                Opart[base + nt * 16 + l15] = (_Float16)o[qt2][nt][r];
            if (l15 == 0)
                lpart[khalf * 65536 + bh * SEQ + ql] = ol[qt2][r];
        }
    }
}

// ---------------------------------------------------------------------------
// combine: attnb[m][e] = bf16( (O1+O2)/(l1+l2) ). 8 elems/thread.
// ---------------------------------------------------------------------------
__global__ __launch_bounds__(256) void combine_kernel(
    const _Float16* __restrict__ O, const float* __restrict__ lp,
    short* __restrict__ attnb)
{
    int i = blockIdx.x * 256 + threadIdx.x;
    int m = i >> 7;
    int e0 = (i & 127) * 8;
    int bi = m >> 11, s = m & 2047, h = e0 >> 6;
    int bh = bi * NH + h;
    float l = lp[bh * SEQ + s] + lp[65536 + bh * SEQ + s];
    float rl = 1.0f / l;
    size_t off = (size_t)m * D_MODEL + e0;
    half8 a = *reinterpret_cast<const half8*>(O + off);
    half8 b = *reinterpret_cast<const half8*>(O + 4096u * 1024u + off);
    short8 out;
#pragma unroll
    for (int j = 0; j < 8; j++)
        out[j] = f2bf(((float)a[j] + (float)b[j]) * rl);
    *reinterpret_cast<short8*>(attnb + off) = out;
}

// ---------------------------------------------------------------------------
// GEMM2 (R16-exact): 128m x 64n, global_load_lds + XOR swizzle. fp32 out.
// ---------------------------------------------------------------------------
__global__ __launch_bounds__(256) void fc_gemm(
    const short* __restrict__ A, const short* __restrict__ W,
    const float* __restrict__ bias, float* __restrict__ out)
{
    __shared__ __align__(16) short As[128 * 64];
    __shared__ __align__(16) short Bs[64 * 64];
    const int tid = threadIdx.x;
    const int m0 = blockIdx.y * 128;
    const int n0 = blockIdx.x * 64;
    const int w = tid >> 6, lane = tid & 63;
    const int quad = lane >> 4, l15 = lane & 15;
    const int wm2 = w >> 1, wn2 = w & 1;

    const int rg = lane >> 3;
    const int sl = lane & 7;
    const int cg = sl ^ rg;

    floatx4 acc[4][2];
#pragma unroll
    for (int i = 0; i < 4; i++)
#pragma unroll
        for (int j = 0; j < 2; j++) acc[i][j] = (floatx4)0.0f;

    for (int k0 = 0; k0 < 1024; k0 += 64) {
        __syncthreads();
#pragma unroll
        for (int j = 0; j < 4; j++) {
            int g = w * 4 + j;
            int r = g * 8 + rg;
            GLDS(&A[(size_t)(m0 + r) * 1024 + k0 + cg * 8], &As[g * 512]);
        }
#pragma unroll
        for (int j = 0; j < 2; j++) {
            int g = w * 2 + j;
            int r = g * 8 + rg;
            GLDS(&W[(size_t)(n0 + r) * 1024 + k0 + cg * 8], &Bs[g * 512]);
        }
        __syncthreads();
#pragma unroll
        for (int kk = 0; kk < 2; kk++) {
            int swz = ((kk * 4 + quad) ^ (l15 & 7)) * 8;
            short8 a[4], b[2];
#pragma unroll
            for (int i = 0; i < 4; i++)
                a[i] = *reinterpret_cast<const short8*>(
                    &As[(wm2 * 64 + i * 16 + l15) * 64 + swz]);
#pragma unroll
            for (int j = 0; j < 2; j++)
                b[j] = *reinterpret_cast<const short8*>(
                    &Bs[(wn2 * 32 + j * 16 + l15) * 64 + swz]);
#pragma unroll
            for (int mt = 0; mt < 4; mt++)
#pragma unroll
                for (int nt = 0; nt < 2; nt++)
                    acc[mt][nt] = __builtin_amdgcn_mfma_f32_16x16x32_bf16(
                        a[mt], b[nt], acc[mt][nt], 0, 0, 0);
        }
    }

#pragma unroll
    for (int nt = 0; nt < 2; nt++) {
        int col = n0 + wn2 * 32 + nt * 16 + l15;
        float bv = bias[col];
#pragma unroll
        for (int mt = 0; mt < 4; mt++) {
#pragma unroll
            for (int r = 0; r < 4; r++) {
                int row = m0 + wm2 * 64 + mt * 16 + quad * 4 + r;
                out[row * 1024 + col] = acc[mt][nt][r] + bv;
            }
        }
    }
}

extern "C" void kernel_launch(void* const* d_in, const int* in_sizes, int n_in,
                              void* d_out, int out_size, void* d_ws, size_t ws_size,
                              hipStream_t stream) {
    const float* x     = (const float*)d_in[0];
    const float* w_qkv = (const float*)d_in[1];
    const float* b_qkv = (const float*)d_in[2];
    const float* w_fc  = (const float*)d_in[3];
    const float* b_fc  = (const float*)d_in[4];
    float* out = (float*)d_out;

    const size_t M1 = 1024u * 1024u;
    short* ws = (short*)d_ws;
    short* Qs    = ws;
    short* Ks    = ws + 4 * M1;
    short* Vt_g  = ws + 8 * M1;
    short* Wfb   = ws + 12 * M1;
    short* Xb    = ws + 13 * M1;
    short* Wqb   = ws + 17 * M1;
    _Float16* Opart = (_Float16*)(ws + 13 * M1);
    float* lpart = (float*)(ws + 21 * M1);
    short* attnb = Qs;   // Qs dead after attn

    cvt_all<<<4096, 256, 0, stream>>>(x, w_qkv, w_fc, Xb, Wqb, Wfb);
    qkv_gemm<<<768, 256, 0, stream>>>(Xb, Wqb, b_qkv, Qs, Ks, Vt_g);
    attn_kernel<<<dim3(16, 16, 2), 256, 0, stream>>>(Qs, Ks, Vt_g, Opart, lpart);
    combine_kernel<<<2048, 256, 0, stream>>>(Opart, lpart, attnb);
    fc_gemm<<<dim3(16, 32), 256, 0, stream>>>(attnb, Wfb, b_fc, out);
}